// Round 7
// baseline (113.684 us; speedup 1.0000x reference)
//
#include <hip/hip_runtime.h>

typedef short short8 __attribute__((ext_vector_type(8)));
typedef float f32x4 __attribute__((ext_vector_type(4)));

#define NN 8
#define CI 64
#define CO 128
#define HH 128
#define WW 128
#define PH 132             // padded (2-halo each side)
#define PW 132
#define MU 0.033333333333333333f

#define TPY 8              // output tile rows
#define TPX 16             // output tile cols
#define HR 12              // halo rows
#define HC 20              // halo cols
#define NPOS (HR * HC)     // 240

#define WS_W_BYTES (9 * 128 * 64 * 2)        // 147456
#define WS_T_OFF   WS_W_BYTES
#define WS_T_BYTES (NN * PH * PW * 4)        // 557568
#define WS_X_OFF   (WS_T_OFF + WS_T_BYTES)   // 705024
#define WS_X_BYTES ((size_t)NN * PH * PW * CI * 2)   // 17842176
#define WS_TOTAL   (WS_X_OFF + WS_X_BYTES)   // ~18.5 MB

__device__ __forceinline__ unsigned short f2bf(float f) {
  unsigned u = __float_as_uint(f);
  u += 0x7fffu + ((u >> 16) & 1u);     // round-to-nearest-even
  return (unsigned short)(u >> 16);
}

__device__ __forceinline__ void g2lds16(const void* g, void* l) {
  __builtin_amdgcn_global_load_lds(
      (const __attribute__((address_space(1))) unsigned int*)g,
      (__attribute__((address_space(3))) unsigned int*)l, 16, 0, 0);
}

// ================= FAST PATH =================
// prep: bf16 NHWC padded repack + channel-sum plane T + weights (coalesced
// layout: ws_w[((tap*8+cb)*2+ks)*64 + lane] short8, lane=hi*16+lo holds
// w[co=cb*16+lo][ic=ks*32+hi*8+j], even taps only)
__global__ __launch_bounds__(256) void prep_kernel(
    const float* __restrict__ in, const float* __restrict__ w,
    unsigned short* __restrict__ ws_w, float* __restrict__ ws_T,
    short8* __restrict__ ws_x) {
  const int b = blockIdx.x, tid = threadIdx.x;
  if (b < 512) {
    __shared__ short8 lx[256][8];            // [px][slot^(px&7)]
    const int n = b >> 6, pair = b & 63;
    const int px = tid;
    const int r = pair * 2 + (px >> 7), x = px & 127;
    const float* src = in + ((size_t)(n * CI) * HH + r) * WW + x;
    float tsum = 0.f;
    #pragma unroll
    for (int g = 0; g < 8; ++g) {
      short8 pk;
      #pragma unroll
      for (int j = 0; j < 8; ++j) {
        const float v = src[(size_t)(g * 8 + j) * (HH * WW)];
        tsum += v;
        pk[j] = (short)f2bf(v);
      }
      lx[px][g ^ (px & 7)] = pk;
    }
    ws_T[(n * PH + r + 2) * PW + (x + 2)] = tsum;
    __syncthreads();
    #pragma unroll
    for (int it = 0; it < 8; ++it) {         // coalesced NHWC store, 16B/lane
      const int G = it * 256 + tid;
      const int px2 = G >> 3, g2 = G & 7;
      const int r2 = pair * 2 + (px2 >> 7), x2 = px2 & 127;
      ws_x[((size_t)(n * PH + r2 + 2) * PW + (x2 + 2)) * 8 + g2] =
          lx[px2][g2 ^ (px2 & 7)];
    }
  } else if (b < 520) {                      // zero the padded borders
    const int n = b - 512;
    const short8 z = {0, 0, 0, 0, 0, 0, 0, 0};
    for (int e = tid; e < 1040 * 8; e += 256) {
      const int px = e >> 3, g = e & 7;
      int y, x;
      if (px < 528) { const int r4 = px / 132; y = (r4 < 2) ? r4 : r4 + 128; x = px - r4 * 132; }
      else { const int q = px - 528; const int c4 = q >> 7; x = (c4 < 2) ? c4 : c4 + 128; y = 2 + (q & 127); }
      ws_x[((size_t)(n * PH + y) * PW + x) * 8 + g] = z;
    }
    for (int e = tid; e < 1040; e += 256) {
      int y, x;
      if (e < 528) { const int r4 = e / 132; y = (r4 < 2) ? r4 : r4 + 128; x = e - r4 * 132; }
      else { const int q = e - 528; const int c4 = q >> 7; x = (c4 < 2) ? c4 : c4 + 128; y = 2 + (q & 127); }
      ws_T[(n * PH + y) * PW + x] = 0.f;
    }
  } else {                                   // weights, coalesced MFMA layout
    const int el = (b - 520) * 256 + tid;    // 0..9215 short8 elements
    const int lane = el & 63;
    const int idx = el >> 6;                 // 0..143
    const int ks = idx & 1, cb = (idx >> 1) & 7, tap = idx >> 4;
    const int lo = lane & 15, hi = lane >> 4;
    const int ky = (tap / 3) * 2, kx = (tap % 3) * 2;
    const float* wp = w + (size_t)((cb * 16 + lo) * 64 + ks * 32 + hi * 8) * 25
                        + ky * 5 + kx;
    short8 pk;
    #pragma unroll
    for (int j = 0; j < 8; ++j) pk[j] = (short)f2bf(wp[j * 25]);
    ((short8*)ws_w)[el] = pk;
  }
}

// conv: wave owns 32 co x 128 px; afrag = 1KB coalesced L2 load
__global__ __launch_bounds__(256, 4) void conv_kernel(
    const unsigned short* __restrict__ ws_w, const float* __restrict__ ws_T,
    const unsigned short* __restrict__ ws_x, float* __restrict__ out) {
  __shared__ short8 in_lds[NPOS * 8];        // 30720 B, [pos][slot^(pos&7)]
  __shared__ float T_lds[NPOS];

  const int tid = threadIdx.x;
  const int wave = tid >> 6, lane = tid & 63;
  const int t = blockIdx.x;                  // 128 tiles: 16 y x 8 x
  const int n = blockIdx.y;
  const int ty0 = (t >> 3) * TPY;
  const int tx0 = (t & 7) * TPX;

  // async halo stage: 30 wave-instrs total, source pre-swizzled
  for (int k = wave; k < NPOS / 8; k += 4) {
    const int pos = k * 8 + (lane >> 3);
    const int r = pos / HC, c = pos - r * HC;
    const int chunk = (lane & 7) ^ (pos & 7);
    const unsigned short* g =
        ws_x + ((size_t)(n * PH + ty0 + r) * PW + (tx0 + c)) * 64 + chunk * 8;
    g2lds16(g, (char*)in_lds + k * 1024);
  }
  if (tid < NPOS) {
    const int r = tid / HC, c = tid - r * HC;
    T_lds[tid] = ws_T[(n * PH + ty0 + r) * PW + (tx0 + c)];
  }
  __syncthreads();                           // drains vmcnt (incl. load_lds)

  const int lo = lane & 15, hi = lane >> 4;

  f32x4 acc[2][8];
  #pragma unroll
  for (int cb = 0; cb < 2; ++cb)
    #pragma unroll
    for (int f = 0; f < 8; ++f) acc[cb][f] = (f32x4){0.f, 0.f, 0.f, 0.f};

  const short8* wsv = (const short8*)ws_w;

  #pragma unroll
  for (int tap = 0; tap < 9; ++tap) {
    const int ty = (tap / 3) * 2, tx = (tap % 3) * 2;
    #pragma unroll
    for (int ks = 0; ks < 2; ++ks) {
      const short8 af0 = wsv[((tap * 8 + wave * 2 + 0) * 2 + ks) * 64 + lane];
      const short8 af1 = wsv[((tap * 8 + wave * 2 + 1) * 2 + ks) * 64 + lane];
      #pragma unroll
      for (int fg = 0; fg < 4; ++fg) {
        const int pos0 = (fg * 2 + 0 + ty) * HC + lo + tx;
        const int pos1 = (fg * 2 + 1 + ty) * HC + lo + tx;
        const short8 bf0 = in_lds[pos0 * 8 + ((ks * 4 + hi) ^ (pos0 & 7))];
        const short8 bf1 = in_lds[pos1 * 8 + ((ks * 4 + hi) ^ (pos1 & 7))];
        acc[0][fg * 2 + 0] = __builtin_amdgcn_mfma_f32_16x16x32_bf16(
            af0, bf0, acc[0][fg * 2 + 0], 0, 0, 0);
        acc[1][fg * 2 + 0] = __builtin_amdgcn_mfma_f32_16x16x32_bf16(
            af1, bf0, acc[1][fg * 2 + 0], 0, 0, 0);
        acc[0][fg * 2 + 1] = __builtin_amdgcn_mfma_f32_16x16x32_bf16(
            af0, bf1, acc[0][fg * 2 + 1], 0, 0, 0);
        acc[1][fg * 2 + 1] = __builtin_amdgcn_mfma_f32_16x16x32_bf16(
            af1, bf1, acc[1][fg * 2 + 1], 0, 0, 0);
      }
    }
  }

  // neighbor term (fp32-exact): depends on (row f, col lo) only
  float nb[8];
  #pragma unroll
  for (int f = 0; f < 8; ++f) {
    float s = 0.f;
    #pragma unroll
    for (int ky = 0; ky < 5; ++ky)
      #pragma unroll
      for (int kx = 0; kx < 5; ++kx)
        if ((ky & 1) | (kx & 1))
          s += T_lds[(f + ky) * HC + (lo + kx)];
    nb[f] = s * MU;
  }

  #pragma unroll
  for (int cb = 0; cb < 2; ++cb) {
    #pragma unroll
    for (int f = 0; f < 8; ++f) {
      const int gy = ty0 + f, gx = tx0 + lo;
      #pragma unroll
      for (int q = 0; q < 4; ++q) {
        const int co = wave * 32 + cb * 16 + hi * 4 + q;
        out[(((size_t)n * CO + co) * HH + gy) * WW + gx] = acc[cb][f][q] + nb[f];
      }
    }
  }
}

// ================= SAFE PATH (Round-2 proven, 705 KB ws) =================
__global__ __launch_bounds__(256) void prep_kernel_safe(
    const float* __restrict__ in, const float* __restrict__ w,
    unsigned short* __restrict__ ws_w, float* __restrict__ ws_T) {
  const int bid = blockIdx.x, tid = threadIdx.x;
  if (bid < 288) {
    const int el = bid * 256 + tid;
    const int tap = el >> 13;
    const int rem = el & 8191;
    const int co = rem >> 6, ic = rem & 63;
    const int ky = (tap / 3) * 2, kx = (tap % 3) * 2;
    ws_w[el] = f2bf(w[(co * 64 + ic) * 25 + ky * 5 + kx]);
  } else {
    const int p = (bid - 288) * 256 + tid;
    const int n = p >> 14;
    const int yx = p & 16383;
    const float* base = in + (size_t)n * CI * (HH * WW) + yx;
    float s = 0.f;
    #pragma unroll
    for (int ic = 0; ic < CI; ++ic) s += base[ic * (HH * WW)];
    ws_T[p] = s;
  }
}

#define SHR 12
#define SHC 36
#define SNPOS (SHR * SHC)

__global__ __launch_bounds__(256, 2) void conv_kernel_safe(
    const float* __restrict__ in, const unsigned short* __restrict__ ws_w,
    const float* __restrict__ ws_T, float* __restrict__ out) {
  __shared__ short8 in_lds[SNPOS * 8];
  __shared__ float T_lds[SNPOS];

  const int tid = threadIdx.x;
  const int t = blockIdx.x;
  const int n = blockIdx.y;
  const int ty0 = (t >> 2) * 8;
  const int tx0 = (t & 3) * 32;

  for (int e = tid; e < SNPOS * 8; e += 256) {
    const int slot = e / SNPOS;
    const int pos = e - slot * SNPOS;
    const int r = pos / SHC, c = pos - r * SHC;
    const int gy = ty0 + r - 2, gx = tx0 + c - 2;
    const bool ok = (gy >= 0 && gy < HH && gx >= 0 && gx < WW);
    const long off = ((long)(n * CI + slot * 8) * HH + gy) * WW + gx;
    short8 pk;
    #pragma unroll
    for (int j = 0; j < 8; ++j) {
      const float v = ok ? in[off + (long)j * (HH * WW)] : 0.f;
      pk[j] = (short)f2bf(v);
    }
    in_lds[pos * 8 + (slot ^ (pos & 7))] = pk;
  }
  for (int e = tid; e < SNPOS; e += 256) {
    const int r = e / SHC, c = e - r * SHC;
    const int gy = ty0 + r - 2, gx = tx0 + c - 2;
    T_lds[e] = (gy >= 0 && gy < HH && gx >= 0 && gx < WW)
                   ? ws_T[((size_t)n * HH + gy) * WW + gx] : 0.f;
  }
  __syncthreads();

  const int wave = tid >> 6;
  const int lane = tid & 63;
  const int lo = lane & 15;
  const int hi = lane >> 4;

  int py[4], pxc[4];
  #pragma unroll
  for (int f = 0; f < 4; ++f) {
    const int pb = wave * 64 + f * 16;
    py[f] = pb >> 5;
    pxc[f] = (pb & 31) + lo;
  }

  f32x4 acc[8][4];
  #pragma unroll
  for (int cb = 0; cb < 8; ++cb)
    #pragma unroll
    for (int f = 0; f < 4; ++f) acc[cb][f] = (f32x4){0.f, 0.f, 0.f, 0.f};

  const short8* wsv = (const short8*)ws_w;

  #pragma unroll
  for (int tap = 0; tap < 9; ++tap) {
    const int ty = (tap / 3) * 2, tx = (tap % 3) * 2;
    #pragma unroll
    for (int ks = 0; ks < 2; ++ks) {
      short8 bfrag[4];
      #pragma unroll
      for (int f = 0; f < 4; ++f) {
        const int pos = (py[f] + ty) * SHC + (pxc[f] + tx);
        bfrag[f] = in_lds[pos * 8 + ((ks * 4 + hi) ^ (pos & 7))];
      }
      #pragma unroll
      for (int cb = 0; cb < 8; ++cb) {
        const short8 afrag = wsv[(tap * 128 + cb * 16 + lo) * 8 + ks * 4 + hi];
        #pragma unroll
        for (int f = 0; f < 4; ++f)
          acc[cb][f] = __builtin_amdgcn_mfma_f32_16x16x32_bf16(
              afrag, bfrag[f], acc[cb][f], 0, 0, 0);
      }
    }
  }

  float nb[4];
  #pragma unroll
  for (int f = 0; f < 4; ++f) {
    float s = 0.f;
    #pragma unroll
    for (int ky = 0; ky < 5; ++ky)
      #pragma unroll
      for (int kx = 0; kx < 5; ++kx)
        if ((ky & 1) | (kx & 1))
          s += T_lds[(py[f] + ky) * SHC + (pxc[f] + kx)];
    nb[f] = s * MU;
  }

  #pragma unroll
  for (int cb = 0; cb < 8; ++cb) {
    #pragma unroll
    for (int f = 0; f < 4; ++f) {
      const int gy = ty0 + py[f];
      const int gx = tx0 + pxc[f];
      #pragma unroll
      for (int q = 0; q < 4; ++q) {
        const int co = cb * 16 + hi * 4 + q;
        out[(((size_t)n * CO + co) * HH + gy) * WW + gx] = acc[cb][f][q] + nb[f];
      }
    }
  }
}

extern "C" void kernel_launch(void* const* d_in, const int* in_sizes, int n_in,
                              void* d_out, int out_size, void* d_ws, size_t ws_size,
                              hipStream_t stream) {
  const float* in = (const float*)d_in[0];
  const float* w  = (const float*)d_in[1];
  float* out = (float*)d_out;
  unsigned short* ws_w = (unsigned short*)d_ws;

  if (ws_size >= WS_TOTAL) {
    float* ws_T = (float*)((char*)d_ws + WS_T_OFF);
    short8* ws_x = (short8*)((char*)d_ws + WS_X_OFF);
    prep_kernel<<<dim3(556), 256, 0, stream>>>(in, w, ws_w, ws_T, ws_x);
    conv_kernel<<<dim3(128, NN), 256, 0, stream>>>(
        ws_w, ws_T, (const unsigned short*)ws_x, out);
  } else {
    float* ws_T = (float*)((char*)d_ws + WS_W_BYTES);
    prep_kernel_safe<<<dim3(288 + 512), 256, 0, stream>>>(in, w, ws_w, ws_T);
    conv_kernel_safe<<<dim3(64, NN), 256, 0, stream>>>(in, ws_w, ws_T, out);
  }
}

// Round 8
// 89.232 us; speedup vs baseline: 1.2740x; 1.2740x over previous
//
#include <hip/hip_runtime.h>

typedef short short8 __attribute__((ext_vector_type(8)));
typedef float f32x4 __attribute__((ext_vector_type(4)));

#define NN 8
#define CI 64
#define CO 128
#define HH 128
#define WW 128
#define PH 132             // padded (2-halo each side)
#define PW 132
#define MU 0.033333333333333333f

#define TPY 8              // output tile rows
#define TPX 32             // output tile cols
#define HR 12              // halo rows
#define HC 36              // halo cols
#define NPOS (HR * HC)     // 432

#define WS_W_BYTES (9 * 128 * 64 * 2)        // 147456
#define WS_T_OFF   WS_W_BYTES
#define WS_T_BYTES (NN * PH * PW * 4)        // 557568
#define WS_X_OFF   (WS_T_OFF + WS_T_BYTES)   // 705024
#define WS_X_BYTES ((size_t)NN * PH * PW * CI * 2)   // 17842176
#define WS_NB_OFF  (WS_X_OFF + WS_X_BYTES)   // 18547200
#define WS_TOTAL   (WS_NB_OFF + WS_T_BYTES)  // ~19.1 MB

__device__ __forceinline__ unsigned short f2bf(float f) {
  unsigned u = __float_as_uint(f);
  u += 0x7fffu + ((u >> 16) & 1u);     // round-to-nearest-even
  return (unsigned short)(u >> 16);
}

__device__ __forceinline__ void g2lds16(const void* g, void* l) {
  __builtin_amdgcn_global_load_lds(
      (const __attribute__((address_space(1))) unsigned int*)g,
      (__attribute__((address_space(3))) unsigned int*)l, 16, 0, 0);
}

// ================= FAST PATH =================
// prep: bf16 NHWC padded repack + channel-sum plane T + weights (coalesced
// layout: ws_w[((tap*8+cb)*2+ks)*64 + lane] short8, lane=hi*16+lo holds
// w[co=cb*16+lo][ic=ks*32+hi*8+j], even taps only)
__global__ __launch_bounds__(256) void prep_kernel(
    const float* __restrict__ in, const float* __restrict__ w,
    unsigned short* __restrict__ ws_w, float* __restrict__ ws_T,
    short8* __restrict__ ws_x) {
  const int b = blockIdx.x, tid = threadIdx.x;
  if (b < 512) {
    __shared__ short8 lx[256][8];            // [px][slot^(px&7)]
    const int n = b >> 6, pair = b & 63;
    const int px = tid;
    const int r = pair * 2 + (px >> 7), x = px & 127;
    const float* src = in + ((size_t)(n * CI) * HH + r) * WW + x;
    float tsum = 0.f;
    #pragma unroll
    for (int g = 0; g < 8; ++g) {
      short8 pk;
      #pragma unroll
      for (int j = 0; j < 8; ++j) {
        const float v = src[(size_t)(g * 8 + j) * (HH * WW)];
        tsum += v;
        pk[j] = (short)f2bf(v);
      }
      lx[px][g ^ (px & 7)] = pk;
    }
    ws_T[(n * PH + r + 2) * PW + (x + 2)] = tsum;
    __syncthreads();
    #pragma unroll
    for (int it = 0; it < 8; ++it) {         // coalesced NHWC store, 16B/lane
      const int G = it * 256 + tid;
      const int px2 = G >> 3, g2 = G & 7;
      const int r2 = pair * 2 + (px2 >> 7), x2 = px2 & 127;
      ws_x[((size_t)(n * PH + r2 + 2) * PW + (x2 + 2)) * 8 + g2] =
          lx[px2][g2 ^ (px2 & 7)];
    }
  } else if (b < 520) {                      // zero the padded borders
    const int n = b - 512;
    const short8 z = {0, 0, 0, 0, 0, 0, 0, 0};
    for (int e = tid; e < 1040 * 8; e += 256) {
      const int px = e >> 3, g = e & 7;
      int y, x;
      if (px < 528) { const int r4 = px / 132; y = (r4 < 2) ? r4 : r4 + 128; x = px - r4 * 132; }
      else { const int q = px - 528; const int c4 = q >> 7; x = (c4 < 2) ? c4 : c4 + 128; y = 2 + (q & 127); }
      ws_x[((size_t)(n * PH + y) * PW + x) * 8 + g] = z;
    }
    for (int e = tid; e < 1040; e += 256) {
      int y, x;
      if (e < 528) { const int r4 = e / 132; y = (r4 < 2) ? r4 : r4 + 128; x = e - r4 * 132; }
      else { const int q = e - 528; const int c4 = q >> 7; x = (c4 < 2) ? c4 : c4 + 128; y = 2 + (q & 127); }
      ws_T[(n * PH + y) * PW + x] = 0.f;
    }
  } else {                                   // weights, coalesced MFMA layout
    const int el = (b - 520) * 256 + tid;    // 0..9215 short8 elements
    const int lane = el & 63;
    const int idx = el >> 6;                 // 0..143
    const int ks = idx & 1, cb = (idx >> 1) & 7, tap = idx >> 4;
    const int lo = lane & 15, hi = lane >> 4;
    const int ky = (tap / 3) * 2, kx = (tap % 3) * 2;
    const float* wp = w + (size_t)((cb * 16 + lo) * 64 + ks * 32 + hi * 8) * 25
                        + ky * 5 + kx;
    short8 pk;
    #pragma unroll
    for (int j = 0; j < 8; ++j) pk[j] = (short)f2bf(wp[j * 25]);
    ((short8*)ws_w)[el] = pk;
  }
}

// nb: per-pixel neighbor plane NB = MU * sum of T over the 16 odd-mask taps
__global__ __launch_bounds__(256) void nb_kernel(
    const float* __restrict__ ws_T, float* __restrict__ ws_nb) {
  const int p = blockIdx.x * 256 + threadIdx.x;   // 131072 interior pixels
  const int n = p >> 14, yx = p & 16383;
  const int y = yx >> 7, x = yx & 127;
  const float* Tb = ws_T + (size_t)(n * PH + y) * PW + x;
  float s = 0.f;
  #pragma unroll
  for (int ky = 0; ky < 5; ++ky)
    #pragma unroll
    for (int kx = 0; kx < 5; ++kx)
      if ((ky & 1) | (kx & 1)) s += Tb[ky * PW + kx];
  ws_nb[(size_t)(n * PH + y + 2) * PW + (x + 2)] = s * MU;
}

// conv: wave owns 32 co x 256 px; afrag = 1KB coalesced burst reused 16x;
// accumulator initialized with the NB plane -> pure-store epilogue
__global__ __launch_bounds__(256, 2) void conv_kernel(
    const unsigned short* __restrict__ ws_w, const float* __restrict__ ws_nb,
    const unsigned short* __restrict__ ws_x, float* __restrict__ out) {
  __shared__ short8 in_lds[NPOS * 8];        // 55296 B, [pos][slot^(pos&7)]

  const int tid = threadIdx.x;
  const int wave = tid >> 6, lane = tid & 63;
  const int t = blockIdx.x;                  // 64 tiles: 16 y x 4 x
  const int n = blockIdx.y;
  const int ty0 = (t >> 2) * TPY;
  const int tx0 = (t & 3) * TPX;

  // async halo stage: 54 x 1KB chunks, source pre-swizzled (R4-proven)
  for (int k = wave; k < 54; k += 4) {
    const int pos = k * 8 + (lane >> 3);
    const int r = pos / HC, c = pos - r * HC;
    const int chunk = (lane & 7) ^ (pos & 7);
    const unsigned short* g =
        ws_x + ((size_t)(n * PH + ty0 + r) * PW + (tx0 + c)) * 64 + chunk * 8;
    g2lds16(g, (char*)in_lds + k * 1024);
  }

  const int lo = lane & 15, hi = lane >> 4;

  // neighbor values (overlap with DMA), folded into accumulator init
  float nb[16];
  #pragma unroll
  for (int pf = 0; pf < 16; ++pf) {
    const int r = pf >> 1, cbase = (pf & 1) * 16;
    nb[pf] = ws_nb[(size_t)(n * PH + ty0 + r + 2) * PW + (tx0 + cbase + lo + 2)];
  }
  f32x4 acc[2][16];
  #pragma unroll
  for (int cb = 0; cb < 2; ++cb)
    #pragma unroll
    for (int pf = 0; pf < 16; ++pf)
      acc[cb][pf] = (f32x4){nb[pf], nb[pf], nb[pf], nb[pf]};

  __syncthreads();                           // drains vmcnt (incl. load_lds)

  const short8* wsv = (const short8*)ws_w;

  #pragma unroll
  for (int tap = 0; tap < 9; ++tap) {
    const int ty = (tap / 3) * 2, tx = (tap % 3) * 2;
    #pragma unroll
    for (int ks = 0; ks < 2; ++ks) {
      const short8 af0 = wsv[((tap * 8 + wave * 2 + 0) * 2 + ks) * 64 + lane];
      const short8 af1 = wsv[((tap * 8 + wave * 2 + 1) * 2 + ks) * 64 + lane];
      #pragma unroll
      for (int pf = 0; pf < 16; ++pf) {
        const int pos = ((pf >> 1) + ty) * HC + ((pf & 1) * 16 + lo + tx);
        const short8 bf = in_lds[pos * 8 + ((ks * 4 + hi) ^ (pos & 7))];
        acc[0][pf] = __builtin_amdgcn_mfma_f32_16x16x32_bf16(
            af0, bf, acc[0][pf], 0, 0, 0);
        acc[1][pf] = __builtin_amdgcn_mfma_f32_16x16x32_bf16(
            af1, bf, acc[1][pf], 0, 0, 0);
      }
    }
  }

  // pure-store epilogue; col pairs (pf&1) dirty full 128B lines per block
  #pragma unroll
  for (int cb = 0; cb < 2; ++cb) {
    #pragma unroll
    for (int pf = 0; pf < 16; ++pf) {
      const int gy = ty0 + (pf >> 1), gx = tx0 + (pf & 1) * 16 + lo;
      #pragma unroll
      for (int q = 0; q < 4; ++q) {
        const int co = wave * 32 + cb * 16 + hi * 4 + q;
        out[(((size_t)n * CO + co) * HH + gy) * WW + gx] = acc[cb][pf][q];
      }
    }
  }
}

// ================= SAFE PATH (Round-2 proven, 705 KB ws) =================
__global__ __launch_bounds__(256) void prep_kernel_safe(
    const float* __restrict__ in, const float* __restrict__ w,
    unsigned short* __restrict__ ws_w, float* __restrict__ ws_T) {
  const int bid = blockIdx.x, tid = threadIdx.x;
  if (bid < 288) {
    const int el = bid * 256 + tid;
    const int tap = el >> 13;
    const int rem = el & 8191;
    const int co = rem >> 6, ic = rem & 63;
    const int ky = (tap / 3) * 2, kx = (tap % 3) * 2;
    ws_w[el] = f2bf(w[(co * 64 + ic) * 25 + ky * 5 + kx]);
  } else {
    const int p = (bid - 288) * 256 + tid;
    const int n = p >> 14;
    const int yx = p & 16383;
    const float* base = in + (size_t)n * CI * (HH * WW) + yx;
    float s = 0.f;
    #pragma unroll
    for (int ic = 0; ic < CI; ++ic) s += base[ic * (HH * WW)];
    ws_T[p] = s;
  }
}

#define SHR 12
#define SHC 36
#define SNPOS (SHR * SHC)

__global__ __launch_bounds__(256, 2) void conv_kernel_safe(
    const float* __restrict__ in, const unsigned short* __restrict__ ws_w,
    const float* __restrict__ ws_T, float* __restrict__ out) {
  __shared__ short8 in_lds[SNPOS * 8];
  __shared__ float T_lds[SNPOS];

  const int tid = threadIdx.x;
  const int t = blockIdx.x;
  const int n = blockIdx.y;
  const int ty0 = (t >> 2) * 8;
  const int tx0 = (t & 3) * 32;

  for (int e = tid; e < SNPOS * 8; e += 256) {
    const int slot = e / SNPOS;
    const int pos = e - slot * SNPOS;
    const int r = pos / SHC, c = pos - r * SHC;
    const int gy = ty0 + r - 2, gx = tx0 + c - 2;
    const bool ok = (gy >= 0 && gy < HH && gx >= 0 && gx < WW);
    const long off = ((long)(n * CI + slot * 8) * HH + gy) * WW + gx;
    short8 pk;
    #pragma unroll
    for (int j = 0; j < 8; ++j) {
      const float v = ok ? in[off + (long)j * (HH * WW)] : 0.f;
      pk[j] = (short)f2bf(v);
    }
    in_lds[pos * 8 + (slot ^ (pos & 7))] = pk;
  }
  for (int e = tid; e < SNPOS; e += 256) {
    const int r = e / SHC, c = e - r * SHC;
    const int gy = ty0 + r - 2, gx = tx0 + c - 2;
    T_lds[e] = (gy >= 0 && gy < HH && gx >= 0 && gx < WW)
                   ? ws_T[((size_t)n * HH + gy) * WW + gx] : 0.f;
  }
  __syncthreads();

  const int wave = tid >> 6;
  const int lane = tid & 63;
  const int lo = lane & 15;
  const int hi = lane >> 4;

  int py[4], pxc[4];
  #pragma unroll
  for (int f = 0; f < 4; ++f) {
    const int pb = wave * 64 + f * 16;
    py[f] = pb >> 5;
    pxc[f] = (pb & 31) + lo;
  }

  f32x4 acc[8][4];
  #pragma unroll
  for (int cb = 0; cb < 8; ++cb)
    #pragma unroll
    for (int f = 0; f < 4; ++f) acc[cb][f] = (f32x4){0.f, 0.f, 0.f, 0.f};

  const short8* wsv = (const short8*)ws_w;

  #pragma unroll
  for (int tap = 0; tap < 9; ++tap) {
    const int ty = (tap / 3) * 2, tx = (tap % 3) * 2;
    #pragma unroll
    for (int ks = 0; ks < 2; ++ks) {
      short8 bfrag[4];
      #pragma unroll
      for (int f = 0; f < 4; ++f) {
        const int pos = (py[f] + ty) * SHC + (pxc[f] + tx);
        bfrag[f] = in_lds[pos * 8 + ((ks * 4 + hi) ^ (pos & 7))];
      }
      #pragma unroll
      for (int cb = 0; cb < 8; ++cb) {
        const short8 afrag = wsv[(tap * 128 + cb * 16 + lo) * 8 + ks * 4 + hi];
        #pragma unroll
        for (int f = 0; f < 4; ++f)
          acc[cb][f] = __builtin_amdgcn_mfma_f32_16x16x32_bf16(
              afrag, bfrag[f], acc[cb][f], 0, 0, 0);
      }
    }
  }

  float nb[4];
  #pragma unroll
  for (int f = 0; f < 4; ++f) {
    float s = 0.f;
    #pragma unroll
    for (int ky = 0; ky < 5; ++ky)
      #pragma unroll
      for (int kx = 0; kx < 5; ++kx)
        if ((ky & 1) | (kx & 1))
          s += T_lds[(py[f] + ky) * SHC + (pxc[f] + kx)];
    nb[f] = s * MU;
  }

  #pragma unroll
  for (int cb = 0; cb < 8; ++cb) {
    #pragma unroll
    for (int f = 0; f < 4; ++f) {
      const int gy = ty0 + py[f];
      const int gx = tx0 + pxc[f];
      #pragma unroll
      for (int q = 0; q < 4; ++q) {
        const int co = cb * 16 + hi * 4 + q;
        out[(((size_t)n * CO + co) * HH + gy) * WW + gx] = acc[cb][f][q] + nb[f];
      }
    }
  }
}

extern "C" void kernel_launch(void* const* d_in, const int* in_sizes, int n_in,
                              void* d_out, int out_size, void* d_ws, size_t ws_size,
                              hipStream_t stream) {
  const float* in = (const float*)d_in[0];
  const float* w  = (const float*)d_in[1];
  float* out = (float*)d_out;
  unsigned short* ws_w = (unsigned short*)d_ws;

  if (ws_size >= WS_TOTAL) {
    float* ws_T = (float*)((char*)d_ws + WS_T_OFF);
    short8* ws_x = (short8*)((char*)d_ws + WS_X_OFF);
    float* ws_nb = (float*)((char*)d_ws + WS_NB_OFF);
    prep_kernel<<<dim3(556), 256, 0, stream>>>(in, w, ws_w, ws_T, ws_x);
    nb_kernel<<<dim3(512), 256, 0, stream>>>(ws_T, ws_nb);
    conv_kernel<<<dim3(64, NN), 256, 0, stream>>>(
        ws_w, ws_nb, (const unsigned short*)ws_x, out);
  } else {
    float* ws_T = (float*)((char*)d_ws + WS_W_BYTES);
    prep_kernel_safe<<<dim3(288 + 512), 256, 0, stream>>>(in, w, ws_w, ws_T);
    conv_kernel_safe<<<dim3(64, NN), 256, 0, stream>>>(in, ws_w, ws_T, out);
  }
}

// Round 10
// 52.917 us; speedup vs baseline: 2.1484x; 1.6863x over previous
//
#include <hip/hip_runtime.h>

typedef short short8 __attribute__((ext_vector_type(8)));
typedef float f32x4 __attribute__((ext_vector_type(4)));

#define NN 8
#define CI 64
#define CO 128
#define HH 128
#define WW 128
#define PH 132             // padded (2-halo each side)
#define PW 132
#define MU 0.033333333333333333f

#define TPY 8              // output tile rows
#define TPX 32             // output tile cols
#define HR 12              // halo rows
#define HC 36              // halo cols
#define NPOS (HR * HC)     // 432

#define WS_W_BYTES (9 * 128 * 64 * 2)        // 147456
#define WS_T_OFF   WS_W_BYTES
#define WS_T_BYTES (NN * PH * PW * 4)        // 557568
#define WS_X_OFF   (WS_T_OFF + WS_T_BYTES)   // 705024
#define WS_X_BYTES ((size_t)NN * PH * PW * CI * 2)   // 17842176
#define WS_NB_OFF  (WS_X_OFF + WS_X_BYTES)   // 18547200
#define WS_TOTAL   (WS_NB_OFF + WS_T_BYTES)  // ~19.1 MB

__device__ __forceinline__ unsigned short f2bf(float f) {
  unsigned u = __float_as_uint(f);
  u += 0x7fffu + ((u >> 16) & 1u);     // round-to-nearest-even
  return (unsigned short)(u >> 16);
}

__device__ __forceinline__ void g2lds16(const void* g, void* l) {
  __builtin_amdgcn_global_load_lds(
      (const __attribute__((address_space(1))) unsigned int*)g,
      (__attribute__((address_space(3))) unsigned int*)l, 16, 0, 0);
}

// ================= FAST PATH =================
// prep: bf16 NHWC padded repack + channel-sum plane T + weights (coalesced
// layout: ws_w[(tap*16 + cb*2 + ks)*64 + lane] short8, lane=hi*16+lo holds
// w[co=cb*16+lo][ic=ks*32+hi*8+j], even taps only)
__global__ __launch_bounds__(256) void prep_kernel(
    const float* __restrict__ in, const float* __restrict__ w,
    unsigned short* __restrict__ ws_w, float* __restrict__ ws_T,
    short8* __restrict__ ws_x) {
  const int b = blockIdx.x, tid = threadIdx.x;
  if (b < 512) {
    __shared__ short8 lx[256][8];            // [px][slot^(px&7)]
    const int n = b >> 6, pair = b & 63;
    const int px = tid;
    const int r = pair * 2 + (px >> 7), x = px & 127;
    const float* src = in + ((size_t)(n * CI) * HH + r) * WW + x;
    float tsum = 0.f;
    #pragma unroll
    for (int g = 0; g < 8; ++g) {
      short8 pk;
      #pragma unroll
      for (int j = 0; j < 8; ++j) {
        const float v = src[(size_t)(g * 8 + j) * (HH * WW)];
        tsum += v;
        pk[j] = (short)f2bf(v);
      }
      lx[px][g ^ (px & 7)] = pk;
    }
    ws_T[(n * PH + r + 2) * PW + (x + 2)] = tsum;
    __syncthreads();
    #pragma unroll
    for (int it = 0; it < 8; ++it) {         // coalesced NHWC store, 16B/lane
      const int G = it * 256 + tid;
      const int px2 = G >> 3, g2 = G & 7;
      const int r2 = pair * 2 + (px2 >> 7), x2 = px2 & 127;
      ws_x[((size_t)(n * PH + r2 + 2) * PW + (x2 + 2)) * 8 + g2] =
          lx[px2][g2 ^ (px2 & 7)];
    }
  } else if (b < 520) {                      // zero the padded borders
    const int n = b - 512;
    const short8 z = {0, 0, 0, 0, 0, 0, 0, 0};
    for (int e = tid; e < 1040 * 8; e += 256) {
      const int px = e >> 3, g = e & 7;
      int y, x;
      if (px < 528) { const int r4 = px / 132; y = (r4 < 2) ? r4 : r4 + 128; x = px - r4 * 132; }
      else { const int q = px - 528; const int c4 = q >> 7; x = (c4 < 2) ? c4 : c4 + 128; y = 2 + (q & 127); }
      ws_x[((size_t)(n * PH + y) * PW + x) * 8 + g] = z;
    }
    for (int e = tid; e < 1040; e += 256) {
      int y, x;
      if (e < 528) { const int r4 = e / 132; y = (r4 < 2) ? r4 : r4 + 128; x = e - r4 * 132; }
      else { const int q = e - 528; const int c4 = q >> 7; x = (c4 < 2) ? c4 : c4 + 128; y = 2 + (q & 127); }
      ws_T[(n * PH + y) * PW + x] = 0.f;
    }
  } else {                                   // weights, coalesced MFMA layout
    const int el = (b - 520) * 256 + tid;    // 0..9215 short8 elements
    const int lane = el & 63;
    const int idx = el >> 6;                 // 0..143 = tap*16 + cb*2 + ks
    const int ks = idx & 1, cb = (idx >> 1) & 7, tap = idx >> 4;
    const int lo = lane & 15, hi = lane >> 4;
    const int ky = (tap / 3) * 2, kx = (tap % 3) * 2;
    const float* wp = w + (size_t)((cb * 16 + lo) * 64 + ks * 32 + hi * 8) * 25
                        + ky * 5 + kx;
    short8 pk;
    #pragma unroll
    for (int j = 0; j < 8; ++j) pk[j] = (short)f2bf(wp[j * 25]);
    ((short8*)ws_w)[el] = pk;
  }
}

// nb: per-pixel neighbor plane NB = MU * sum of T over the 16 odd-mask taps
__global__ __launch_bounds__(256) void nb_kernel(
    const float* __restrict__ ws_T, float* __restrict__ ws_nb) {
  const int p = blockIdx.x * 256 + threadIdx.x;   // 131072 interior pixels
  const int n = p >> 14, yx = p & 16383;
  const int y = yx >> 7, x = yx & 127;
  const float* Tb = ws_T + (size_t)(n * PH + y) * PW + x;
  float s = 0.f;
  #pragma unroll
  for (int ky = 0; ky < 5; ++ky)
    #pragma unroll
    for (int kx = 0; kx < 5; ++kx)
      if ((ky & 1) | (kx & 1)) s += Tb[ky * PW + kx];
  ws_nb[(size_t)(n * PH + y + 2) * PW + (x + 2)] = s * MU;
}

// conv v3: R4 decomposition (wave owns 64 px x all co of this block's half),
// co split across 2 blocks; weights AND halo DMA'd to LDS; inner loop is
// pure LDS + MFMA (zero global loads after the barrier).
__global__ __launch_bounds__(256, 1) void conv_kernel(
    const unsigned short* __restrict__ ws_w, const float* __restrict__ ws_nb,
    const unsigned short* __restrict__ ws_x, float* __restrict__ out) {
  __shared__ short8 in_lds[NPOS * 8];        // 55296 B, [pos][slot^(pos&7)]
  __shared__ short8 w_lds[72 * 64];          // 73728 B, [tap*8+cbl*2+ks][lane]

  const int tid = threadIdx.x;
  const int wave = tid >> 6, lane = tid & 63;
  const int t = blockIdx.x;                  // 64 tiles: 16 y x 4 x
  const int n = blockIdx.y;
  const int cob = blockIdx.z;                // co half: 0 or 1
  const int ty0 = (t >> 2) * TPY;
  const int tx0 = (t & 3) * TPX;

  // async halo stage: 54 x 1KB chunks, source pre-swizzled (R4-proven)
  for (int k = wave; k < 54; k += 4) {
    const int pos = k * 8 + (lane >> 3);
    const int r = pos / HC, c = pos - r * HC;
    const int chunk = (lane & 7) ^ (pos & 7);
    const unsigned short* g =
        ws_x + ((size_t)(n * PH + ty0 + r) * PW + (tx0 + c)) * 64 + chunk * 8;
    g2lds16(g, (char*)in_lds + k * 1024);
  }
  // async weight stage: this half's 72 x 1KB chunks, already in lane order
  for (int k = wave; k < 72; k += 4) {
    const int tap = k >> 3, jj = k & 7;      // jj = cbl*2 + ks
    const short8* g = (const short8*)ws_w + ((tap * 16 + cob * 8 + jj) * 64 + lane);
    g2lds16(g, (char*)w_lds + k * 1024);
  }

  const int lo = lane & 15, hi = lane >> 4;

  int py[4], pxc[4];
  #pragma unroll
  for (int f = 0; f < 4; ++f) {
    const int pb = wave * 64 + f * 16;       // wave owns 64 px, 4 frags of 16
    py[f] = pb >> 5;
    pxc[f] = (pb & 31) + lo;
  }

  // neighbor term from precomputed plane (overlaps DMA), into acc init
  float nb[4];
  #pragma unroll
  for (int f = 0; f < 4; ++f)
    nb[f] = ws_nb[(size_t)(n * PH + ty0 + py[f] + 2) * PW + (tx0 + pxc[f] + 2)];

  f32x4 acc[4][4];
  #pragma unroll
  for (int cb = 0; cb < 4; ++cb)
    #pragma unroll
    for (int f = 0; f < 4; ++f)
      acc[cb][f] = (f32x4){nb[f], nb[f], nb[f], nb[f]};

  __syncthreads();                           // drains vmcnt (incl. load_lds)

  #pragma unroll
  for (int tap = 0; tap < 9; ++tap) {
    const int ty = (tap / 3) * 2, tx = (tap % 3) * 2;
    #pragma unroll
    for (int ks = 0; ks < 2; ++ks) {
      short8 afrag[4];
      #pragma unroll
      for (int cb = 0; cb < 4; ++cb)
        afrag[cb] = w_lds[(tap * 8 + cb * 2 + ks) * 64 + lane];
      short8 bfrag[4];
      #pragma unroll
      for (int f = 0; f < 4; ++f) {
        const int pos = (py[f] + ty) * HC + (pxc[f] + tx);
        bfrag[f] = in_lds[pos * 8 + ((ks * 4 + hi) ^ (pos & 7))];
      }
      #pragma unroll
      for (int cb = 0; cb < 4; ++cb)
        #pragma unroll
        for (int f = 0; f < 4; ++f)
          acc[cb][f] = __builtin_amdgcn_mfma_f32_16x16x32_bf16(
              afrag[cb], bfrag[f], acc[cb][f], 0, 0, 0);
    }
  }

  // pure-store epilogue (R4's measured-clean pattern)
  #pragma unroll
  for (int cb = 0; cb < 4; ++cb) {
    #pragma unroll
    for (int f = 0; f < 4; ++f) {
      const int gy = ty0 + py[f];
      const int gx = tx0 + pxc[f];
      #pragma unroll
      for (int q = 0; q < 4; ++q) {
        const int co = cob * 64 + cb * 16 + hi * 4 + q;
        out[(((size_t)n * CO + co) * HH + gy) * WW + gx] = acc[cb][f][q];
      }
    }
  }
}

// ================= SAFE PATH (Round-2 proven, 705 KB ws) =================
__global__ __launch_bounds__(256) void prep_kernel_safe(
    const float* __restrict__ in, const float* __restrict__ w,
    unsigned short* __restrict__ ws_w, float* __restrict__ ws_T) {
  const int bid = blockIdx.x, tid = threadIdx.x;
  if (bid < 288) {
    const int el = bid * 256 + tid;
    const int tap = el >> 13;
    const int rem = el & 8191;
    const int co = rem >> 6, ic = rem & 63;
    const int ky = (tap / 3) * 2, kx = (tap % 3) * 2;
    ws_w[el] = f2bf(w[(co * 64 + ic) * 25 + ky * 5 + kx]);
  } else {
    const int p = (bid - 288) * 256 + tid;
    const int n = p >> 14;
    const int yx = p & 16383;
    const float* base = in + (size_t)n * CI * (HH * WW) + yx;
    float s = 0.f;
    #pragma unroll
    for (int ic = 0; ic < CI; ++ic) s += base[ic * (HH * WW)];
    ws_T[p] = s;
  }
}

#define SHR 12
#define SHC 36
#define SNPOS (SHR * SHC)

__global__ __launch_bounds__(256, 2) void conv_kernel_safe(
    const float* __restrict__ in, const unsigned short* __restrict__ ws_w,
    const float* __restrict__ ws_T, float* __restrict__ out) {
  __shared__ short8 in_lds[SNPOS * 8];
  __shared__ float T_lds[SNPOS];

  const int tid = threadIdx.x;
  const int t = blockIdx.x;
  const int n = blockIdx.y;
  const int ty0 = (t >> 2) * 8;
  const int tx0 = (t & 3) * 32;

  for (int e = tid; e < SNPOS * 8; e += 256) {
    const int slot = e / SNPOS;
    const int pos = e - slot * SNPOS;
    const int r = pos / SHC, c = pos - r * SHC;
    const int gy = ty0 + r - 2, gx = tx0 + c - 2;
    const bool ok = (gy >= 0 && gy < HH && gx >= 0 && gx < WW);
    const long off = ((long)(n * CI + slot * 8) * HH + gy) * WW + gx;
    short8 pk;
    #pragma unroll
    for (int j = 0; j < 8; ++j) {
      const float v = ok ? in[off + (long)j * (HH * WW)] : 0.f;
      pk[j] = (short)f2bf(v);
    }
    in_lds[pos * 8 + (slot ^ (pos & 7))] = pk;
  }
  for (int e = tid; e < SNPOS; e += 256) {
    const int r = e / SHC, c = e - r * SHC;
    const int gy = ty0 + r - 2, gx = tx0 + c - 2;
    T_lds[e] = (gy >= 0 && gy < HH && gx >= 0 && gx < WW)
                   ? ws_T[((size_t)n * HH + gy) * WW + gx] : 0.f;
  }
  __syncthreads();

  const int wave = tid >> 6;
  const int lane = tid & 63;
  const int lo = lane & 15;
  const int hi = lane >> 4;

  int py[4], pxc[4];
  #pragma unroll
  for (int f = 0; f < 4; ++f) {
    const int pb = wave * 64 + f * 16;
    py[f] = pb >> 5;
    pxc[f] = (pb & 31) + lo;
  }

  f32x4 acc[8][4];
  #pragma unroll
  for (int cb = 0; cb < 8; ++cb)
    #pragma unroll
    for (int f = 0; f < 4; ++f) acc[cb][f] = (f32x4){0.f, 0.f, 0.f, 0.f};

  const short8* wsv = (const short8*)ws_w;

  #pragma unroll
  for (int tap = 0; tap < 9; ++tap) {
    const int ty = (tap / 3) * 2, tx = (tap % 3) * 2;
    #pragma unroll
    for (int ks = 0; ks < 2; ++ks) {
      short8 bfrag[4];
      #pragma unroll
      for (int f = 0; f < 4; ++f) {
        const int pos = (py[f] + ty) * SHC + (pxc[f] + tx);
        bfrag[f] = in_lds[pos * 8 + ((ks * 4 + hi) ^ (pos & 7))];
      }
      #pragma unroll
      for (int cb = 0; cb < 8; ++cb) {
        const short8 afrag = wsv[(tap * 128 + cb * 16 + lo) * 8 + ks * 4 + hi];
        #pragma unroll
        for (int f = 0; f < 4; ++f)
          acc[cb][f] = __builtin_amdgcn_mfma_f32_16x16x32_bf16(
              afrag, bfrag[f], acc[cb][f], 0, 0, 0);
      }
    }
  }

  float nb[4];
  #pragma unroll
  for (int f = 0; f < 4; ++f) {
    float s = 0.f;
    #pragma unroll
    for (int ky = 0; ky < 5; ++ky)
      #pragma unroll
      for (int kx = 0; kx < 5; ++kx)
        if ((ky & 1) | (kx & 1))
          s += T_lds[(py[f] + ky) * SHC + (pxc[f] + kx)];
    nb[f] = s * MU;
  }

  #pragma unroll
  for (int cb = 0; cb < 8; ++cb) {
    #pragma unroll
    for (int f = 0; f < 4; ++f) {
      const int gy = ty0 + py[f];
      const int gx = tx0 + pxc[f];
      #pragma unroll
      for (int q = 0; q < 4; ++q) {
        const int co = cb * 16 + hi * 4 + q;
        out[(((size_t)n * CO + co) * HH + gy) * WW + gx] = acc[cb][f][q] + nb[f];
      }
    }
  }
}

extern "C" void kernel_launch(void* const* d_in, const int* in_sizes, int n_in,
                              void* d_out, int out_size, void* d_ws, size_t ws_size,
                              hipStream_t stream) {
  const float* in = (const float*)d_in[0];
  const float* w  = (const float*)d_in[1];
  float* out = (float*)d_out;
  unsigned short* ws_w = (unsigned short*)d_ws;

  if (ws_size >= WS_TOTAL) {
    float* ws_T = (float*)((char*)d_ws + WS_T_OFF);
    short8* ws_x = (short8*)((char*)d_ws + WS_X_OFF);
    float* ws_nb = (float*)((char*)d_ws + WS_NB_OFF);
    prep_kernel<<<dim3(556), 256, 0, stream>>>(in, w, ws_w, ws_T, ws_x);
    nb_kernel<<<dim3(512), 256, 0, stream>>>(ws_T, ws_nb);
    conv_kernel<<<dim3(64, NN, 2), 256, 0, stream>>>(
        ws_w, ws_nb, (const unsigned short*)ws_x, out);
  } else {
    float* ws_T = (float*)((char*)d_ws + WS_W_BYTES);
    prep_kernel_safe<<<dim3(288 + 512), 256, 0, stream>>>(in, w, ws_w, ws_T);
    conv_kernel_safe<<<dim3(64, NN), 256, 0, stream>>>(in, ws_w, ws_T, out);
  }
}

// Round 12
// 51.962 us; speedup vs baseline: 2.1878x; 1.0184x over previous
//
#include <hip/hip_runtime.h>

typedef short short8 __attribute__((ext_vector_type(8)));
typedef float f32x4 __attribute__((ext_vector_type(4)));

#define NN 8
#define CI 64
#define CO 128
#define HH 128
#define WW 128
#define PH 132             // padded (2-halo each side)
#define PW 132
#define MU 0.033333333333333333f

#define TPY 8              // output tile rows
#define TPX 32             // output tile cols
#define HR 12              // halo rows
#define HC 36              // halo cols
#define NPOS (HR * HC)     // 432

#define WS_W_BYTES (9 * 128 * 64 * 2)        // 147456
#define WS_T_OFF   WS_W_BYTES
#define WS_T_BYTES (NN * PH * PW * 4)        // 557568
#define WS_X_OFF   (WS_T_OFF + WS_T_BYTES)   // 705024
#define WS_X_BYTES ((size_t)NN * PH * PW * CI * 2)   // 17842176
#define WS_NB_OFF  (WS_X_OFF + WS_X_BYTES)   // 18547200
#define WS_TOTAL   (WS_NB_OFF + WS_T_BYTES)  // ~19.1 MB

__device__ __forceinline__ unsigned short f2bf(float f) {
  unsigned u = __float_as_uint(f);
  u += 0x7fffu + ((u >> 16) & 1u);     // round-to-nearest-even
  return (unsigned short)(u >> 16);
}

__device__ __forceinline__ void g2lds16(const void* g, void* l) {
  __builtin_amdgcn_global_load_lds(
      (const __attribute__((address_space(1))) unsigned int*)g,
      (__attribute__((address_space(3))) unsigned int*)l, 16, 0, 0);
}
__device__ __forceinline__ void g2lds4(const void* g, void* l) {
  __builtin_amdgcn_global_load_lds(
      (const __attribute__((address_space(1))) unsigned int*)g,
      (__attribute__((address_space(3))) unsigned int*)l, 4, 0, 0);
}

// ================= FAST PATH =================
// prep: bf16 NHWC padded repack + channel-sum plane T + weights (coalesced
// layout: ws_w[(tap*16 + cb*2 + ks)*64 + lane] short8, lane=hi*16+lo holds
// w[co=cb*16+lo][ic=ks*32+hi*8+j], even taps only)
__global__ __launch_bounds__(256) void prep_kernel(
    const float* __restrict__ in, const float* __restrict__ w,
    unsigned short* __restrict__ ws_w, float* __restrict__ ws_T,
    short8* __restrict__ ws_x) {
  const int b = blockIdx.x, tid = threadIdx.x;
  if (b < 512) {
    __shared__ short8 lx[256][8];            // [px][slot^(px&7)]
    const int n = b >> 6, pair = b & 63;
    const int px = tid;
    const int r = pair * 2 + (px >> 7), x = px & 127;
    const float* src = in + ((size_t)(n * CI) * HH + r) * WW + x;
    float tsum = 0.f;
    #pragma unroll
    for (int g = 0; g < 8; ++g) {
      short8 pk;
      #pragma unroll
      for (int j = 0; j < 8; ++j) {
        const float v = src[(size_t)(g * 8 + j) * (HH * WW)];
        tsum += v;
        pk[j] = (short)f2bf(v);
      }
      lx[px][g ^ (px & 7)] = pk;
    }
    ws_T[(n * PH + r + 2) * PW + (x + 2)] = tsum;
    __syncthreads();
    #pragma unroll
    for (int it = 0; it < 8; ++it) {         // coalesced NHWC store, 16B/lane
      const int G = it * 256 + tid;
      const int px2 = G >> 3, g2 = G & 7;
      const int r2 = pair * 2 + (px2 >> 7), x2 = px2 & 127;
      ws_x[((size_t)(n * PH + r2 + 2) * PW + (x2 + 2)) * 8 + g2] =
          lx[px2][g2 ^ (px2 & 7)];
    }
  } else if (b < 520) {                      // zero the padded borders
    const int n = b - 512;
    const short8 z = {0, 0, 0, 0, 0, 0, 0, 0};
    for (int e = tid; e < 1040 * 8; e += 256) {
      const int px = e >> 3, g = e & 7;
      int y, x;
      if (px < 528) { const int r4 = px / 132; y = (r4 < 2) ? r4 : r4 + 128; x = px - r4 * 132; }
      else { const int q = px - 528; const int c4 = q >> 7; x = (c4 < 2) ? c4 : c4 + 128; y = 2 + (q & 127); }
      ws_x[((size_t)(n * PH + y) * PW + x) * 8 + g] = z;
    }
    for (int e = tid; e < 1040; e += 256) {
      int y, x;
      if (e < 528) { const int r4 = e / 132; y = (r4 < 2) ? r4 : r4 + 128; x = e - r4 * 132; }
      else { const int q = e - 528; const int c4 = q >> 7; x = (c4 < 2) ? c4 : c4 + 128; y = 2 + (q & 127); }
      ws_T[(n * PH + y) * PW + x] = 0.f;
    }
  } else {                                   // weights, coalesced MFMA layout
    const int el = (b - 520) * 256 + tid;    // 0..9215 short8 elements
    const int lane = el & 63;
    const int idx = el >> 6;                 // 0..143 = tap*16 + cb*2 + ks
    const int ks = idx & 1, cb = (idx >> 1) & 7, tap = idx >> 4;
    const int lo = lane & 15, hi = lane >> 4;
    const int ky = (tap / 3) * 2, kx = (tap % 3) * 2;
    const float* wp = w + (size_t)((cb * 16 + lo) * 64 + ks * 32 + hi * 8) * 25
                        + ky * 5 + kx;
    short8 pk;
    #pragma unroll
    for (int j = 0; j < 8; ++j) pk[j] = (short)f2bf(wp[j * 25]);
    ((short8*)ws_w)[el] = pk;
  }
}

// nb: per-pixel neighbor plane NB = MU * sum of T over the 16 odd-mask taps
__global__ __launch_bounds__(256) void nb_kernel(
    const float* __restrict__ ws_T, float* __restrict__ ws_nb) {
  const int p = blockIdx.x * 256 + threadIdx.x;   // 131072 interior pixels
  const int n = p >> 14, yx = p & 16383;
  const int y = yx >> 7, x = yx & 127;
  const float* Tb = ws_T + (size_t)(n * PH + y) * PW + x;
  float s = 0.f;
  #pragma unroll
  for (int ky = 0; ky < 5; ++ky)
    #pragma unroll
    for (int kx = 0; kx < 5; ++kx)
      if ((ky & 1) | (kx & 1)) s += Tb[ky * PW + kx];
  ws_nb[(size_t)(n * PH + y + 2) * PW + (x + 2)] = s * MU;
}

// conv v4: persistent, 256 blocks (1/CU), each owns 32 co (cob quarter) and
// loops 8 spatial units. Weights staged once; halo+NB double-buffered with
// counted vmcnt so DMA/compute/stores overlap. MFMA operands swapped
// (A=input, B=weights) so D rows=px, cols=co -> dwordx4 row stores.
__global__ __launch_bounds__(256, 1) void conv_kernel(
    const unsigned short* __restrict__ ws_w, const float* __restrict__ ws_nb,
    const unsigned short* __restrict__ ws_x, float* __restrict__ out) {
  __shared__ short8 halo[2][NPOS * 8];       // 2 x 55296 B
  __shared__ float  nbt[2][256];             // 2 x 1024 B (8 rows x 32 cols)
  __shared__ short8 wl[36 * 64];             // 36864 B
  __shared__ short8 dummy[2 * 64];           // 2048 B (vmcnt-count padding)

  const int tid = threadIdx.x;
  const int wave = tid >> 6, lane = tid & 63;
  const int bid = blockIdx.x;                // 256
  const int cob = bid >> 6;                  // 0..3: 32-co quarter
  const int idx0 = bid & 63;
  const int lo = lane & 15, hi = lane >> 4;

  // ---- stage this quarter's weights once: 9 x 1KB chunks per wave ----
  for (int k = wave; k < 36; k += 4) {
    const int tap = k >> 2, r = k & 3;       // r = cbl*2 + ks
    const short8* g = (const short8*)ws_w + ((tap * 16 + cob * 4 + r) * 64 + lane);
    g2lds16(g, (char*)wl + k * 1024);
  }

  // per-unit DMA: exactly 15 wave-instrs (14 halo incl. 2 dummies + 1 nb)
  auto issue_unit = [&](int su, int b) {
    const int t = su & 63, n = su >> 6;
    const int ty0 = (t >> 2) * TPY, tx0 = (t & 3) * TPX;
    for (int k = wave; k < 56; k += 4) {     // 14 per wave
      const int kk = (k < 54) ? k : (k - 54);
      char* dst = (k < 54) ? ((char*)halo[b] + k * 1024)
                           : ((char*)dummy + (k - 54) * 1024);
      const int pos = kk * 8 + (lane >> 3);
      const int r = pos / HC, c = pos - r * HC;
      const int chunk = (lane & 7) ^ (pos & 7);
      const unsigned short* g =
          ws_x + ((size_t)(n * PH + ty0 + r) * PW + (tx0 + c)) * 64 + chunk * 8;
      g2lds16(g, dst);
    }
    {                                        // nb rows 2w, 2w+1 (1 instr/wave)
      const int rr = 2 * wave + (lane >> 5), cc = lane & 31;
      const float* g = ws_nb + (size_t)(n * PH + ty0 + rr + 2) * PW + (tx0 + cc + 2);
      g2lds4(g, (char*)nbt[b] + wave * 256);
    }
  };

  // prologue: unit 0 into buf 0; full drain once
  issue_unit(idx0 * 8, 0);
  asm volatile("s_waitcnt vmcnt(0)" ::: "memory");
  __builtin_amdgcn_s_barrier();
  __builtin_amdgcn_sched_barrier(0);

  int cur = 0;
  for (int u = 0; u < 8; ++u) {
    if (u > 0) {
      // outstanding/wave: DMA_u(15) oldest, stores_{u-1}(8) newest.
      // vmcnt(8) completes exactly the 15 DMAs; stores stay in flight.
      asm volatile("s_waitcnt vmcnt(8)" ::: "memory");
      __builtin_amdgcn_s_barrier();
      __builtin_amdgcn_sched_barrier(0);
    }
    if (u < 7) issue_unit(idx0 * 8 + u + 1, cur ^ 1);

    const int su = idx0 * 8 + u;
    const int t = su & 63, n = su >> 6;
    const int ty0 = (t >> 2) * TPY, tx0 = (t & 3) * TPX;

    // acc init from NB tile (co-independent; rows=px after operand swap)
    f32x4 acc[2][4];
    #pragma unroll
    for (int f = 0; f < 4; ++f) {
      const int pb = wave * 64 + f * 16;
      const f32x4 nbv =
          *(const f32x4*)&nbt[cur][(pb >> 5) * 32 + (pb & 31) + hi * 4];
      acc[0][f] = nbv;
      acc[1][f] = nbv;
    }

    #pragma unroll
    for (int tap = 0; tap < 9; ++tap) {
      const int ty = (tap / 3) * 2, tx = (tap % 3) * 2;
      #pragma unroll
      for (int ks = 0; ks < 2; ++ks) {
        short8 wf0 = wl[(tap * 4 + 0 + ks) * 64 + lane];
        short8 wf1 = wl[(tap * 4 + 2 + ks) * 64 + lane];
        #pragma unroll
        for (int f = 0; f < 4; ++f) {
          const int pb = wave * 64 + f * 16;
          const int pos = ((pb >> 5) + ty) * HC + ((pb & 31) + lo + tx);
          const short8 af = halo[cur][pos * 8 + ((ks * 4 + hi) ^ (pos & 7))];
          acc[0][f] = __builtin_amdgcn_mfma_f32_16x16x32_bf16(
              af, wf0, acc[0][f], 0, 0, 0);
          acc[1][f] = __builtin_amdgcn_mfma_f32_16x16x32_bf16(
              af, wf1, acc[1][f], 0, 0, 0);
        }
      }
    }

    // epilogue: 8 dwordx4 stores/thread, full 128B rows per block
    #pragma unroll
    for (int cb = 0; cb < 2; ++cb) {
      #pragma unroll
      for (int f = 0; f < 4; ++f) {
        const int pb = wave * 64 + f * 16;
        const int gy = ty0 + (pb >> 5);
        const int gx = tx0 + (pb & 31) + hi * 4;
        const int co = cob * 32 + cb * 16 + lo;
        *(f32x4*)&out[(((size_t)n * CO + co) * HH + gy) * WW + gx] = acc[cb][f];
      }
    }
    cur ^= 1;
  }
}

// ================= SAFE PATH (Round-2 proven, 705 KB ws) =================
__global__ __launch_bounds__(256) void prep_kernel_safe(
    const float* __restrict__ in, const float* __restrict__ w,
    unsigned short* __restrict__ ws_w, float* __restrict__ ws_T) {
  const int bid = blockIdx.x, tid = threadIdx.x;
  if (bid < 288) {
    const int el = bid * 256 + tid;
    const int tap = el >> 13;
    const int rem = el & 8191;
    const int co = rem >> 6, ic = rem & 63;
    const int ky = (tap / 3) * 2, kx = (tap % 3) * 2;
    ws_w[el] = f2bf(w[(co * 64 + ic) * 25 + ky * 5 + kx]);
  } else {
    const int p = (bid - 288) * 256 + tid;
    const int n = p >> 14;
    const int yx = p & 16383;
    const float* base = in + (size_t)n * CI * (HH * WW) + yx;
    float s = 0.f;
    #pragma unroll
    for (int ic = 0; ic < CI; ++ic) s += base[ic * (HH * WW)];
    ws_T[p] = s;
  }
}

#define SHR 12
#define SHC 36
#define SNPOS (SHR * SHC)

__global__ __launch_bounds__(256, 2) void conv_kernel_safe(
    const float* __restrict__ in, const unsigned short* __restrict__ ws_w,
    const float* __restrict__ ws_T, float* __restrict__ out) {
  __shared__ short8 in_lds[SNPOS * 8];
  __shared__ float T_lds[SNPOS];

  const int tid = threadIdx.x;
  const int t = blockIdx.x;
  const int n = blockIdx.y;
  const int ty0 = (t >> 2) * 8;
  const int tx0 = (t & 3) * 32;

  for (int e = tid; e < SNPOS * 8; e += 256) {
    const int slot = e / SNPOS;
    const int pos = e - slot * SNPOS;
    const int r = pos / SHC, c = pos - r * SHC;
    const int gy = ty0 + r - 2, gx = tx0 + c - 2;
    const bool ok = (gy >= 0 && gy < HH && gx >= 0 && gx < WW);
    const long off = ((long)(n * CI + slot * 8) * HH + gy) * WW + gx;
    short8 pk;
    #pragma unroll
    for (int j = 0; j < 8; ++j) {
      const float v = ok ? in[off + (long)j * (HH * WW)] : 0.f;
      pk[j] = (short)f2bf(v);
    }
    in_lds[pos * 8 + (slot ^ (pos & 7))] = pk;
  }
  for (int e = tid; e < SNPOS; e += 256) {
    const int r = e / SHC, c = e - r * SHC;
    const int gy = ty0 + r - 2, gx = tx0 + c - 2;
    T_lds[e] = (gy >= 0 && gy < HH && gx >= 0 && gx < WW)
                   ? ws_T[((size_t)n * HH + gy) * WW + gx] : 0.f;
  }
  __syncthreads();

  const int wave = tid >> 6;
  const int lane = tid & 63;
  const int lo = lane & 15;
  const int hi = lane >> 4;

  int py[4], pxc[4];
  #pragma unroll
  for (int f = 0; f < 4; ++f) {
    const int pb = wave * 64 + f * 16;
    py[f] = pb >> 5;
    pxc[f] = (pb & 31) + lo;
  }

  f32x4 acc[8][4];
  #pragma unroll
  for (int cb = 0; cb < 8; ++cb)
    #pragma unroll
    for (int f = 0; f < 4; ++f) acc[cb][f] = (f32x4){0.f, 0.f, 0.f, 0.f};

  const short8* wsv = (const short8*)ws_w;

  #pragma unroll
  for (int tap = 0; tap < 9; ++tap) {
    const int ty = (tap / 3) * 2, tx = (tap % 3) * 2;
    #pragma unroll
    for (int ks = 0; ks < 2; ++ks) {
      short8 bfrag[4];
      #pragma unroll
      for (int f = 0; f < 4; ++f) {
        const int pos = (py[f] + ty) * SHC + (pxc[f] + tx);
        bfrag[f] = in_lds[pos * 8 + ((ks * 4 + hi) ^ (pos & 7))];
      }
      #pragma unroll
      for (int cb = 0; cb < 8; ++cb) {
        const short8 afrag = wsv[(tap * 128 + cb * 16 + lo) * 8 + ks * 4 + hi];
        #pragma unroll
        for (int f = 0; f < 4; ++f)
          acc[cb][f] = __builtin_amdgcn_mfma_f32_16x16x32_bf16(
              afrag, bfrag[f], acc[cb][f], 0, 0, 0);
      }
    }
  }

  float nb[4];
  #pragma unroll
  for (int f = 0; f < 4; ++f) {
    float s = 0.f;
    #pragma unroll
    for (int ky = 0; ky < 5; ++ky)
      #pragma unroll
      for (int kx = 0; kx < 5; ++kx)
        if ((ky & 1) | (kx & 1))
          s += T_lds[(py[f] + ky) * SHC + (pxc[f] + kx)];
    nb[f] = s * MU;
  }

  #pragma unroll
  for (int cb = 0; cb < 8; ++cb) {
    #pragma unroll
    for (int f = 0; f < 4; ++f) {
      const int gy = ty0 + py[f];
      const int gx = tx0 + pxc[f];
      #pragma unroll
      for (int q = 0; q < 4; ++q) {
        const int co = cb * 16 + hi * 4 + q;
        out[(((size_t)n * CO + co) * HH + gy) * WW + gx] = acc[cb][f][q] + nb[f];
      }
    }
  }
}

extern "C" void kernel_launch(void* const* d_in, const int* in_sizes, int n_in,
                              void* d_out, int out_size, void* d_ws, size_t ws_size,
                              hipStream_t stream) {
  const float* in = (const float*)d_in[0];
  const float* w  = (const float*)d_in[1];
  float* out = (float*)d_out;
  unsigned short* ws_w = (unsigned short*)d_ws;

  if (ws_size >= WS_TOTAL) {
    float* ws_T = (float*)((char*)d_ws + WS_T_OFF);
    short8* ws_x = (short8*)((char*)d_ws + WS_X_OFF);
    float* ws_nb = (float*)((char*)d_ws + WS_NB_OFF);
    prep_kernel<<<dim3(556), 256, 0, stream>>>(in, w, ws_w, ws_T, ws_x);
    nb_kernel<<<dim3(512), 256, 0, stream>>>(ws_T, ws_nb);
    conv_kernel<<<dim3(256), 256, 0, stream>>>(
        ws_w, ws_nb, (const unsigned short*)ws_x, out);
  } else {
    float* ws_T = (float*)((char*)d_ws + WS_W_BYTES);
    prep_kernel_safe<<<dim3(288 + 512), 256, 0, stream>>>(in, w, ws_w, ws_T);
    conv_kernel_safe<<<dim3(64, NN), 256, 0, stream>>>(in, ws_w, ws_T, out);
  }
}

// Round 13
// 49.286 us; speedup vs baseline: 2.3066x; 1.0543x over previous
//
#include <hip/hip_runtime.h>

typedef short short8 __attribute__((ext_vector_type(8)));
typedef float f32x4 __attribute__((ext_vector_type(4)));

#define NN 8
#define CI 64
#define CO 128
#define HH 128
#define WW 128
#define PH 132             // padded (2-halo each side)
#define PW 132
#define MU 0.033333333333333333f

#define WS_W_BYTES (9 * 128 * 64 * 2)        // 147456
#define WS_T_OFF   WS_W_BYTES
#define WS_T_BYTES (NN * PH * PW * 4)        // 557568
#define WS_X_OFF   (WS_T_OFF + WS_T_BYTES)   // 705024
#define WS_X_BYTES ((size_t)NN * PH * PW * CI * 2)   // 17842176
#define WS_NB_OFF  (WS_X_OFF + WS_X_BYTES)   // 18547200
#define WS_TOTAL   (WS_NB_OFF + WS_T_BYTES)  // ~19.1 MB

__device__ __forceinline__ unsigned short f2bf(float f) {
  unsigned u = __float_as_uint(f);
  u += 0x7fffu + ((u >> 16) & 1u);     // round-to-nearest-even
  return (unsigned short)(u >> 16);
}

__device__ __forceinline__ void g2lds16(const void* g, void* l) {
  __builtin_amdgcn_global_load_lds(
      (const __attribute__((address_space(1))) unsigned int*)g,
      (__attribute__((address_space(3))) unsigned int*)l, 16, 0, 0);
}
__device__ __forceinline__ void g2lds4(const void* g, void* l) {
  __builtin_amdgcn_global_load_lds(
      (const __attribute__((address_space(1))) unsigned int*)g,
      (__attribute__((address_space(3))) unsigned int*)l, 4, 0, 0);
}

// ================= FAST PATH =================
// prep: bf16 NHWC padded repack + channel-sum plane T + weights (coalesced
// layout: ws_w[(tap*16 + cb*2 + ks)*64 + lane] short8, lane=hi*16+lo holds
// w[co=cb*16+lo][ic=ks*32+hi*8+j], even taps only)
__global__ __launch_bounds__(256) void prep_kernel(
    const float* __restrict__ in, const float* __restrict__ w,
    unsigned short* __restrict__ ws_w, float* __restrict__ ws_T,
    short8* __restrict__ ws_x) {
  const int b = blockIdx.x, tid = threadIdx.x;
  if (b < 512) {
    __shared__ short8 lx[256][8];            // [px][slot^(px&7)]
    const int n = b >> 6, pair = b & 63;
    const int px = tid;
    const int r = pair * 2 + (px >> 7), x = px & 127;
    const float* src = in + ((size_t)(n * CI) * HH + r) * WW + x;
    float tsum = 0.f;
    #pragma unroll
    for (int g = 0; g < 8; ++g) {
      short8 pk;
      #pragma unroll
      for (int j = 0; j < 8; ++j) {
        const float v = src[(size_t)(g * 8 + j) * (HH * WW)];
        tsum += v;
        pk[j] = (short)f2bf(v);
      }
      lx[px][g ^ (px & 7)] = pk;
    }
    ws_T[(n * PH + r + 2) * PW + (x + 2)] = tsum;
    __syncthreads();
    #pragma unroll
    for (int it = 0; it < 8; ++it) {         // coalesced NHWC store, 16B/lane
      const int G = it * 256 + tid;
      const int px2 = G >> 3, g2 = G & 7;
      const int r2 = pair * 2 + (px2 >> 7), x2 = px2 & 127;
      ws_x[((size_t)(n * PH + r2 + 2) * PW + (x2 + 2)) * 8 + g2] =
          lx[px2][g2 ^ (px2 & 7)];
    }
  } else if (b < 520) {                      // zero the padded borders
    const int n = b - 512;
    const short8 z = {0, 0, 0, 0, 0, 0, 0, 0};
    for (int e = tid; e < 1040 * 8; e += 256) {
      const int px = e >> 3, g = e & 7;
      int y, x;
      if (px < 528) { const int r4 = px / 132; y = (r4 < 2) ? r4 : r4 + 128; x = px - r4 * 132; }
      else { const int q = px - 528; const int c4 = q >> 7; x = (c4 < 2) ? c4 : c4 + 128; y = 2 + (q & 127); }
      ws_x[((size_t)(n * PH + y) * PW + x) * 8 + g] = z;
    }
    for (int e = tid; e < 1040; e += 256) {
      int y, x;
      if (e < 528) { const int r4 = e / 132; y = (r4 < 2) ? r4 : r4 + 128; x = e - r4 * 132; }
      else { const int q = e - 528; const int c4 = q >> 7; x = (c4 < 2) ? c4 : c4 + 128; y = 2 + (q & 127); }
      ws_T[(n * PH + y) * PW + x] = 0.f;
    }
  } else {                                   // weights, coalesced MFMA layout
    const int el = (b - 520) * 256 + tid;    // 0..9215 short8 elements
    const int lane = el & 63;
    const int idx = el >> 6;                 // 0..143 = tap*16 + cb*2 + ks
    const int ks = idx & 1, cb = (idx >> 1) & 7, tap = idx >> 4;
    const int lo = lane & 15, hi = lane >> 4;
    const int ky = (tap / 3) * 2, kx = (tap % 3) * 2;
    const float* wp = w + (size_t)((cb * 16 + lo) * 64 + ks * 32 + hi * 8) * 25
                        + ky * 5 + kx;
    short8 pk;
    #pragma unroll
    for (int j = 0; j < 8; ++j) pk[j] = (short)f2bf(wp[j * 25]);
    ((short8*)ws_w)[el] = pk;
  }
}

// nb: per-pixel neighbor plane NB = MU * sum of T over the 16 odd-mask taps
__global__ __launch_bounds__(256) void nb_kernel(
    const float* __restrict__ ws_T, float* __restrict__ ws_nb) {
  const int p = blockIdx.x * 256 + threadIdx.x;   // 131072 interior pixels
  const int n = p >> 14, yx = p & 16383;
  const int y = yx >> 7, x = yx & 127;
  const float* Tb = ws_T + (size_t)(n * PH + y) * PW + x;
  float s = 0.f;
  #pragma unroll
  for (int ky = 0; ky < 5; ++ky)
    #pragma unroll
    for (int kx = 0; kx < 5; ++kx)
      if ((ky & 1) | (kx & 1)) s += Tb[ky * PW + kx];
  ws_nb[(size_t)(n * PH + y + 2) * PW + (x + 2)] = s * MU;
}

// conv v5: 2 blocks/CU (2 waves/SIMD) for latency hiding. Block = 4 waves,
// each owning 32 px x 32 co of a 4x32 unit; quarter-weights in LDS staged
// once; halo 8x36 single-buffered; plain __syncthreads per unit; overlap
// via cross-block TLP. Swapped MFMA (A=input, B=weights) -> dwordx4 stores.
__global__ __launch_bounds__(256, 2) void conv_kernel(
    const unsigned short* __restrict__ ws_w, const float* __restrict__ ws_nb,
    const unsigned short* __restrict__ ws_x, float* __restrict__ out) {
  __shared__ short8 halo[288 * 8];     // 36864 B: 8 rows x 36 cols, swizzled
  __shared__ short8 wl[36 * 64];       // 36864 B: [tap*4 + cb*2 + ks][lane]
  __shared__ float  nbt[128];          // 512 B: 4 rows x 32 cols

  const int tid = threadIdx.x;
  const int wave = tid >> 6, lane = tid & 63;
  const int bid = blockIdx.x;          // 1024
  const int cob = bid >> 8;            // 0..3: 32-co quarter
  const int s   = bid & 255;           // spatial set (4 units each)
  const int lo = lane & 15, hi = lane >> 4;

  // stage this quarter's weights once (first unit's syncthreads drains)
  for (int k = wave; k < 36; k += 4) {
    const int tap = k >> 2, r = k & 3;       // r = cbl*2 + ks
    const short8* g = (const short8*)ws_w + ((tap * 16 + cob * 4 + r) * 64 + lane);
    g2lds16(g, (char*)wl + k * 1024);
  }

  for (int j = 0; j < 4; ++j) {
    const int su = s * 4 + j;                // 0..1023
    const int n = su >> 7, rem = su & 127;
    const int ty0 = (rem >> 2) * 4;          // 32 y-units of 4 rows
    const int tx0 = (rem & 3) * 32;          // 4 x-units of 32 cols

    // halo DMA: 36 x 1KB chunks (9 per wave), source pre-swizzled
    for (int k = wave; k < 36; k += 4) {
      const int pos = k * 8 + (lane >> 3);
      const int r = pos / 36, c = pos - r * 36;
      const int chunk = (lane & 7) ^ (pos & 7);
      const unsigned short* g =
          ws_x + ((size_t)(n * PH + ty0 + r) * PW + (tx0 + c)) * 64 + chunk * 8;
      g2lds16(g, (char*)halo + k * 1024);
    }
    if (wave < 2) {                          // nb tile: 2 rows per instr
      const float* g = ws_nb
          + (size_t)(n * PH + ty0 + 2 * wave + (lane >> 5) + 2) * PW
          + (tx0 + (lane & 31) + 2);
      g2lds4(g, (char*)nbt + wave * 256);
    }
    __syncthreads();                         // drains vmcnt (DMA complete)

    // acc init from NB (rows=px after operand swap)
    f32x4 acc[2][2];
    #pragma unroll
    for (int f = 0; f < 2; ++f) {
      const f32x4 nbv = *(const f32x4*)&nbt[wave * 32 + f * 16 + hi * 4];
      acc[0][f] = nbv;
      acc[1][f] = nbv;
    }

    #pragma unroll
    for (int tap = 0; tap < 9; ++tap) {
      const int ty = (tap / 3) * 2, tx = (tap % 3) * 2;
      #pragma unroll
      for (int ks = 0; ks < 2; ++ks) {
        const short8 wf0 = wl[(tap * 4 + 0 + ks) * 64 + lane];
        const short8 wf1 = wl[(tap * 4 + 2 + ks) * 64 + lane];
        #pragma unroll
        for (int f = 0; f < 2; ++f) {
          const int pos = (wave + ty) * 36 + (f * 16 + lo + tx);
          const short8 af = halo[pos * 8 + ((ks * 4 + hi) ^ (pos & 7))];
          acc[0][f] = __builtin_amdgcn_mfma_f32_16x16x32_bf16(
              af, wf0, acc[0][f], 0, 0, 0);
          acc[1][f] = __builtin_amdgcn_mfma_f32_16x16x32_bf16(
              af, wf1, acc[1][f], 0, 0, 0);
        }
      }
    }

    // stores: f0+f1 cover the full 32-px row -> whole 128B lines per block
    #pragma unroll
    for (int cb = 0; cb < 2; ++cb) {
      #pragma unroll
      for (int f = 0; f < 2; ++f) {
        const int gy = ty0 + wave;
        const int gx = tx0 + f * 16 + hi * 4;
        const int co = cob * 32 + cb * 16 + lo;
        *(f32x4*)&out[(((size_t)n * CO + co) * HH + gy) * WW + gx] = acc[cb][f];
      }
    }
    __syncthreads();                         // protect halo/nbt overwrite
  }
}

// ================= SAFE PATH (Round-2 proven, 705 KB ws) =================
__global__ __launch_bounds__(256) void prep_kernel_safe(
    const float* __restrict__ in, const float* __restrict__ w,
    unsigned short* __restrict__ ws_w, float* __restrict__ ws_T) {
  const int bid = blockIdx.x, tid = threadIdx.x;
  if (bid < 288) {
    const int el = bid * 256 + tid;
    const int tap = el >> 13;
    const int rem = el & 8191;
    const int co = rem >> 6, ic = rem & 63;
    const int ky = (tap / 3) * 2, kx = (tap % 3) * 2;
    ws_w[el] = f2bf(w[(co * 64 + ic) * 25 + ky * 5 + kx]);
  } else {
    const int p = (bid - 288) * 256 + tid;
    const int n = p >> 14;
    const int yx = p & 16383;
    const float* base = in + (size_t)n * CI * (HH * WW) + yx;
    float s = 0.f;
    #pragma unroll
    for (int ic = 0; ic < CI; ++ic) s += base[ic * (HH * WW)];
    ws_T[p] = s;
  }
}

#define SHR 12
#define SHC 36
#define SNPOS (SHR * SHC)

__global__ __launch_bounds__(256, 2) void conv_kernel_safe(
    const float* __restrict__ in, const unsigned short* __restrict__ ws_w,
    const float* __restrict__ ws_T, float* __restrict__ out) {
  __shared__ short8 in_lds[SNPOS * 8];
  __shared__ float T_lds[SNPOS];

  const int tid = threadIdx.x;
  const int t = blockIdx.x;
  const int n = blockIdx.y;
  const int ty0 = (t >> 2) * 8;
  const int tx0 = (t & 3) * 32;

  for (int e = tid; e < SNPOS * 8; e += 256) {
    const int slot = e / SNPOS;
    const int pos = e - slot * SNPOS;
    const int r = pos / SHC, c = pos - r * SHC;
    const int gy = ty0 + r - 2, gx = tx0 + c - 2;
    const bool ok = (gy >= 0 && gy < HH && gx >= 0 && gx < WW);
    const long off = ((long)(n * CI + slot * 8) * HH + gy) * WW + gx;
    short8 pk;
    #pragma unroll
    for (int j = 0; j < 8; ++j) {
      const float v = ok ? in[off + (long)j * (HH * WW)] : 0.f;
      pk[j] = (short)f2bf(v);
    }
    in_lds[pos * 8 + (slot ^ (pos & 7))] = pk;
  }
  for (int e = tid; e < SNPOS; e += 256) {
    const int r = e / SHC, c = e - r * SHC;
    const int gy = ty0 + r - 2, gx = tx0 + c - 2;
    T_lds[e] = (gy >= 0 && gy < HH && gx >= 0 && gx < WW)
                   ? ws_T[((size_t)n * HH + gy) * WW + gx] : 0.f;
  }
  __syncthreads();

  const int wave = tid >> 6;
  const int lane = tid & 63;
  const int lo = lane & 15;
  const int hi = lane >> 4;

  int py[4], pxc[4];
  #pragma unroll
  for (int f = 0; f < 4; ++f) {
    const int pb = wave * 64 + f * 16;
    py[f] = pb >> 5;
    pxc[f] = (pb & 31) + lo;
  }

  f32x4 acc[8][4];
  #pragma unroll
  for (int cb = 0; cb < 8; ++cb)
    #pragma unroll
    for (int f = 0; f < 4; ++f) acc[cb][f] = (f32x4){0.f, 0.f, 0.f, 0.f};

  const short8* wsv = (const short8*)ws_w;

  #pragma unroll
  for (int tap = 0; tap < 9; ++tap) {
    const int ty = (tap / 3) * 2, tx = (tap % 3) * 2;
    #pragma unroll
    for (int ks = 0; ks < 2; ++ks) {
      short8 bfrag[4];
      #pragma unroll
      for (int f = 0; f < 4; ++f) {
        const int pos = (py[f] + ty) * SHC + (pxc[f] + tx);
        bfrag[f] = in_lds[pos * 8 + ((ks * 4 + hi) ^ (pos & 7))];
      }
      #pragma unroll
      for (int cb = 0; cb < 8; ++cb) {
        const short8 afrag = wsv[(tap * 128 + cb * 16 + lo) * 8 + ks * 4 + hi];
        #pragma unroll
        for (int f = 0; f < 4; ++f)
          acc[cb][f] = __builtin_amdgcn_mfma_f32_16x16x32_bf16(
              afrag, bfrag[f], acc[cb][f], 0, 0, 0);
      }
    }
  }

  float nb[4];
  #pragma unroll
  for (int f = 0; f < 4; ++f) {
    float s = 0.f;
    #pragma unroll
    for (int ky = 0; ky < 5; ++ky)
      #pragma unroll
      for (int kx = 0; kx < 5; ++kx)
        if ((ky & 1) | (kx & 1))
          s += T_lds[(py[f] + ky) * SHC + (pxc[f] + kx)];
    nb[f] = s * MU;
  }

  #pragma unroll
  for (int cb = 0; cb < 8; ++cb) {
    #pragma unroll
    for (int f = 0; f < 4; ++f) {
      const int gy = ty0 + py[f];
      const int gx = tx0 + pxc[f];
      #pragma unroll
      for (int q = 0; q < 4; ++q) {
        const int co = cb * 16 + hi * 4 + q;
        out[(((size_t)n * CO + co) * HH + gy) * WW + gx] = acc[cb][f][q] + nb[f];
      }
    }
  }
}

extern "C" void kernel_launch(void* const* d_in, const int* in_sizes, int n_in,
                              void* d_out, int out_size, void* d_ws, size_t ws_size,
                              hipStream_t stream) {
  const float* in = (const float*)d_in[0];
  const float* w  = (const float*)d_in[1];
  float* out = (float*)d_out;
  unsigned short* ws_w = (unsigned short*)d_ws;

  if (ws_size >= WS_TOTAL) {
    float* ws_T = (float*)((char*)d_ws + WS_T_OFF);
    short8* ws_x = (short8*)((char*)d_ws + WS_X_OFF);
    float* ws_nb = (float*)((char*)d_ws + WS_NB_OFF);
    prep_kernel<<<dim3(556), 256, 0, stream>>>(in, w, ws_w, ws_T, ws_x);
    nb_kernel<<<dim3(512), 256, 0, stream>>>(ws_T, ws_nb);
    conv_kernel<<<dim3(1024), 256, 0, stream>>>(
        ws_w, ws_nb, (const unsigned short*)ws_x, out);
  } else {
    float* ws_T = (float*)((char*)d_ws + WS_W_BYTES);
    prep_kernel_safe<<<dim3(288 + 512), 256, 0, stream>>>(in, w, ws_w, ws_T);
    conv_kernel_safe<<<dim3(64, NN), 256, 0, stream>>>(in, ws_w, ws_T, out);
  }
}